// Round 7
// baseline (451.365 us; speedup 1.0000x reference)
//
#include <hip/hip_runtime.h>
#include <cstdint>

// out = in + 0.1f * N(0,1) reproducing jax.random.normal(key(42), shape, f32)
// (partitionable threefry; bits = x0^x1; verified PASS @ absmax 0.0078125).
// NUMERICS ARE FROZEN: same float ops in same order per element as the
// passing round-6 kernel. This round only reduces VALU instruction count:
//   - rotl via v_alignbit_b32 (1 instr, bit-identical)
//   - 8 elts/thread, branch-free uniform phase (interleavable chains)

__device__ __forceinline__ uint32_t rotl32(uint32_t x, uint32_t r) {
    // rotate-left(r) == funnel-shift-right(x:x, 32-r) == v_alignbit_b32
    return __builtin_amdgcn_alignbit(x, x, 32u - r);
}

// Threefry-2x32, 20 rounds, key (0, 42); returns x0 ^ x1 (JAX 32-bit draw).
__device__ __forceinline__ uint32_t threefry_xor(uint32_t ctr_lo) {
    const uint32_t K0 = 0u;
    const uint32_t K1 = 42u;
    const uint32_t K2 = 0x1BD11BDAu ^ K0 ^ K1;   // 0x1BD11BF0
    // x0 = 0 + K0 = 0; round 1 does x0 += x1  ==>  fold: x0 = x1_init.
    uint32_t x1 = ctr_lo + K1;
    uint32_t x0 = x1;
    x1 = rotl32(x1, 13); x1 ^= x0;
#define TF_R(r) { x0 += x1; x1 = rotl32(x1, r); x1 ^= x0; }
    TF_R(15) TF_R(26) TF_R(6)
    x0 += K1; x1 += K2 + 1u;
    TF_R(17) TF_R(29) TF_R(16) TF_R(24)
    x0 += K2; x1 += K0 + 2u;
    TF_R(13) TF_R(15) TF_R(26) TF_R(6)
    x0 += K0; x1 += K1 + 3u;
    TF_R(17) TF_R(29) TF_R(16) TF_R(24)
    x0 += K1; x1 += K2 + 4u;
    TF_R(13) TF_R(15) TF_R(26) TF_R(6)
    x0 += K2; x1 += K0 + 5u;
#undef TF_R
    return x0 ^ x1;
}

// uniform in [lo, 1) exactly as JAX: f in [0,1), u = max(lo, fmaf(f,2,lo))
__device__ __forceinline__ float bits_to_u(uint32_t bits) {
    const float lo = -0.99999994f;               // nextafter(-1, 0)
    uint32_t fb = (bits >> 9) | 0x3F800000u;
    float f = __uint_as_float(fb) - 1.0f;
    float u = fmaf(f, 2.0f, lo);                 // exact mul + single-round add
    return fmaxf(u, lo);
}

// XLA f32 ErfInv (Giles 2010 polynomial), exact XLA constants.
__device__ __forceinline__ float erfinv32(float x) {
    float w = -log1pf(-x * x);
    float p;
    if (w < 5.0f) {
        w -= 2.5f;
        p = 2.81022636e-08f;
        p = fmaf(p, w, 3.43273939e-07f);
        p = fmaf(p, w, -3.5233877e-06f);
        p = fmaf(p, w, -4.39150654e-06f);
        p = fmaf(p, w, 0.00021858087f);
        p = fmaf(p, w, -0.00125372503f);
        p = fmaf(p, w, -0.00417768164f);
        p = fmaf(p, w, 0.246640727f);
        p = fmaf(p, w, 1.50140941f);
    } else {
        w = sqrtf(w) - 3.0f;
        p = -0.000200214257f;
        p = fmaf(p, w, 0.000100950558f);
        p = fmaf(p, w, 0.00134934322f);
        p = fmaf(p, w, -0.00367342844f);
        p = fmaf(p, w, 0.00573950773f);
        p = fmaf(p, w, -0.0076224613f);
        p = fmaf(p, w, 0.00943887047f);
        p = fmaf(p, w, 1.00167406f);
        p = fmaf(p, w, 2.83297682f);
    }
    return p * x;
}

__global__ __launch_bounds__(256) void noise_add_kernel(
    const float* __restrict__ in, float* __restrict__ out, unsigned n8) {
    unsigned t = blockIdx.x * blockDim.x + threadIdx.x;
    if (t >= n8) return;

    const float4* in4 = reinterpret_cast<const float4*>(in);
    const float4 va = in4[2u * t];
    const float4 vb = in4[2u * t + 1u];
    const uint32_t base = t * 8u;

    // Phase 1: 8 branch-free uniform draws (8 independent threefry chains —
    // compiler can interleave for ILP; no control flow in this loop).
    float u[8];
#pragma unroll
    for (int k = 0; k < 8; ++k)
        u[k] = bits_to_u(threefry_xor(base + (uint32_t)k));

    // Phase 2: erfinv (has the rare w>=5 branch) + scale + add.
    const float sqrt2 = 1.41421356f;             // 0x3FB504F3
    float nrm[8];
#pragma unroll
    for (int k = 0; k < 8; ++k)
        nrm[k] = sqrt2 * erfinv32(u[k]);

    float4 oa, ob;
    oa.x = fmaf(0.1f, nrm[0], va.x);
    oa.y = fmaf(0.1f, nrm[1], va.y);
    oa.z = fmaf(0.1f, nrm[2], va.z);
    oa.w = fmaf(0.1f, nrm[3], va.w);
    ob.x = fmaf(0.1f, nrm[4], vb.x);
    ob.y = fmaf(0.1f, nrm[5], vb.y);
    ob.z = fmaf(0.1f, nrm[6], vb.z);
    ob.w = fmaf(0.1f, nrm[7], vb.w);
    float4* out4 = reinterpret_cast<float4*>(out);
    out4[2u * t]      = oa;
    out4[2u * t + 1u] = ob;
}

extern "C" void kernel_launch(void* const* d_in, const int* in_sizes, int n_in,
                              void* d_out, int out_size, void* d_ws, size_t ws_size,
                              hipStream_t stream) {
    const float* in = (const float*)d_in[0];
    float* out = (float*)d_out;
    const unsigned n  = (unsigned)in_sizes[0];   // 50331648, divisible by 8
    const unsigned n8 = n / 8u;
    const unsigned block = 256;
    const unsigned grid = (n8 + block - 1) / block;
    noise_add_kernel<<<grid, block, 0, stream>>>(in, out, n8);
}

// Round 8
// 328.097 us; speedup vs baseline: 1.3757x; 1.3757x over previous
//
#include <hip/hip_runtime.h>
#include <cstdint>

// out = in + 0.1f * N(0,1) reproducing jax.random.normal(key(42), shape, f32)
// (partitionable threefry; bits = x0^x1). R6 passed @ absmax 0.0078125 (232us).
// R7 (alignbit + 8/thr) neutral->-5%: rotate was already fused; revert to R6
// structure. R8 experiment: replace OCML log1pf (~35 VALU instrs) with
//   s = 1.0f + t   (EXACT by Sterbenz for t<=-0.5, i.e. the high-derivative tail)
//   w = -ln2 * v_log_f32(s)
// Δw <~ 1e-6 => Δz <~ 1e-7 except possible w≈5 branch-straddle (same mechanism
// as the existing 0.0078 absmax). Everything else bit-identical to R6.

__device__ __forceinline__ uint32_t rotl32(uint32_t x, uint32_t r) {
    return __builtin_amdgcn_alignbit(x, x, 32u - r);   // 1x v_alignbit_b32
}

// Threefry-2x32, 20 rounds, key (0, 42); returns x0 ^ x1 (JAX 32-bit draw).
__device__ __forceinline__ uint32_t threefry_xor(uint32_t ctr_lo) {
    const uint32_t K0 = 0u;
    const uint32_t K1 = 42u;
    const uint32_t K2 = 0x1BD11BDAu ^ K0 ^ K1;   // 0x1BD11BF0
    // x0 = 0 + K0 = 0; round 1: x0 += x1  ==> fold: x0 = x1_init.
    uint32_t x1 = ctr_lo + K1;
    uint32_t x0 = x1;
    x1 = rotl32(x1, 13); x1 ^= x0;
#define TF_R(r) { x0 += x1; x1 = rotl32(x1, r); x1 ^= x0; }
    TF_R(15) TF_R(26) TF_R(6)
    x0 += K1; x1 += K2 + 1u;
    TF_R(17) TF_R(29) TF_R(16) TF_R(24)
    x0 += K2; x1 += K0 + 2u;
    TF_R(13) TF_R(15) TF_R(26) TF_R(6)
    x0 += K0; x1 += K1 + 3u;
    TF_R(17) TF_R(29) TF_R(16) TF_R(24)
    x0 += K1; x1 += K2 + 4u;
    TF_R(13) TF_R(15) TF_R(26) TF_R(6)
    x0 += K2; x1 += K0 + 5u;
#undef TF_R
    return x0 ^ x1;
}

// XLA f32 ErfInv (Giles polynomial, exact XLA constants); log1p replaced by
// exact-add + hardware log2 (see header comment).
__device__ __forceinline__ float erfinv32(float x) {
    float t = -(x * x);                    // same rounding as reference's -x^2
    float s = 1.0f + t;                    // exact in tail (Sterbenz), <=0.5ulp else
    float w = __log2f(s) * -0.693147182464599609375f;   // -ln2 * log2(s)
    float p;
    if (w < 5.0f) {
        w -= 2.5f;
        p = 2.81022636e-08f;
        p = fmaf(p, w, 3.43273939e-07f);
        p = fmaf(p, w, -3.5233877e-06f);
        p = fmaf(p, w, -4.39150654e-06f);
        p = fmaf(p, w, 0.00021858087f);
        p = fmaf(p, w, -0.00125372503f);
        p = fmaf(p, w, -0.00417768164f);
        p = fmaf(p, w, 0.246640727f);
        p = fmaf(p, w, 1.50140941f);
    } else {
        w = sqrtf(w) - 3.0f;
        p = -0.000200214257f;
        p = fmaf(p, w, 0.000100950558f);
        p = fmaf(p, w, 0.00134934322f);
        p = fmaf(p, w, -0.00367342844f);
        p = fmaf(p, w, 0.00573950773f);
        p = fmaf(p, w, -0.0076224613f);
        p = fmaf(p, w, 0.00943887047f);
        p = fmaf(p, w, 1.00167406f);
        p = fmaf(p, w, 2.83297682f);
    }
    return p * x;
}

__global__ __launch_bounds__(256) void noise_add_kernel(
    const float* __restrict__ in, float* __restrict__ out, unsigned n4) {
    unsigned t = blockIdx.x * blockDim.x + threadIdx.x;
    if (t >= n4) return;

    const float4 v = reinterpret_cast<const float4*>(in)[t];
    const uint32_t base = t * 4u;

    const float lo    = -0.99999994f;   // nextafter(-1, 0) in f32
    const float sqrt2 = 1.41421356f;    // 0x3FB504F3

    float r[4];
    const float vi[4] = {v.x, v.y, v.z, v.w};
#pragma unroll
    for (int k = 0; k < 4; ++k) {
        uint32_t bits = threefry_xor(base + (uint32_t)k);
        uint32_t fb   = (bits >> 9) | 0x3F800000u;
        float f = __uint_as_float(fb) - 1.0f;       // [0, 1)
        float u = fmaf(f, 2.0f, lo);                // exact mul + single-round add
        u = fmaxf(u, lo);
        float n = sqrt2 * erfinv32(u);
        r[k] = fmaf(0.1f, n, vi[k]);
    }

    float4 o;
    o.x = r[0]; o.y = r[1]; o.z = r[2]; o.w = r[3];
    reinterpret_cast<float4*>(out)[t] = o;
}

extern "C" void kernel_launch(void* const* d_in, const int* in_sizes, int n_in,
                              void* d_out, int out_size, void* d_ws, size_t ws_size,
                              hipStream_t stream) {
    const float* in = (const float*)d_in[0];
    float* out = (float*)d_out;
    const unsigned n  = (unsigned)in_sizes[0];   // 50331648, divisible by 4
    const unsigned n4 = n / 4u;
    const unsigned block = 256;
    const unsigned grid = (n4 + block - 1) / block;
    noise_add_kernel<<<grid, block, 0, stream>>>(in, out, n4);
}